// Round 9
// baseline (205.985 us; speedup 1.0000x reference)
//
#include <hip/hip_runtime.h>

#define D_MODEL 768
#define BN 16
#define NROWS 32768
#define SCALE 0.1f
#define LN_EPS 1e-5f
#define TPB 256
#define WAVES 4
#define ROWS_PER_BLOCK 64                  // 4 waves x 16 rows
#define NBLOCKS (NROWS / ROWS_PER_BLOCK)   // 512 blocks -> 2 blocks/CU
#define KCH 24                             // 768/32 K-chunks for down-proj

using f32x4  = __attribute__((ext_vector_type(4))) float;
using bf16x8 = __attribute__((ext_vector_type(8))) short;

// round-to-nearest-even fp32 -> bf16 bits (finite inputs)
__device__ __forceinline__ unsigned short f2bf(float f) {
    unsigned int u = __float_as_uint(f);
    unsigned int r = (u + 0x7FFFu + ((u >> 16) & 1u)) >> 16;
    return (unsigned short)r;
}

__device__ __forceinline__ void ld4(const float* p, float* d) {
    float4 v = *(const float4*)p;
    d[0] = v.x; d[1] = v.y; d[2] = v.z; d[3] = v.w;
}

// R8 post-mortem: the VALU/shfl structure bottoms out at ~78-94us: weights
// re-read from LDS per 2 rows (96 ds_read_b128) + ~120 ds_bpermute shfls per
// pass saturate the DS pipe. MFMA restructure: one wave = 16 rows; weight
// B-frags read ONCE per 16 rows (24 ds_read_b128, 16x less); k-reduction
// inside MFMA (2 shfls for LN stats, zero butterflies). bf16 inputs, fp32
// accum; LN folded: down = relu(rs*(P - mean*G) + D + bd).
__global__ __launch_bounds__(TPB)
void adapter_fused(const float* __restrict__ x,
                   const float* __restrict__ gamma,
                   const float* __restrict__ beta,
                   const float* __restrict__ w_down,
                   const float* __restrict__ b_down,
                   const float* __restrict__ w_up,
                   const float* __restrict__ b_up,
                   float* __restrict__ out)
{
    // [k][d] bf16(gamma*wd): B-frag for down. 776-pad -> 2-way banks (free).
    __shared__ __align__(16) unsigned short s_wdb[BN][776];        // 24.8 KB
    // [d][k] bf16(SCALE*wu): B-frag for up. 24-short rows (48B, b128-aligned);
    // shorts 16..23 zeroed (q=2 lanes), rows 768/769 zeroed (q=3 at d=767).
    __shared__ __align__(16) unsigned short s_wub[770][24];        // 37.0 KB
    // per-wave dn tile [r][k] bf16, 24-short rows, pads zeroed
    __shared__ __align__(16) unsigned short s_dn2[WAVES][17][24];  // 3.3 KB
    __shared__ float s_sbu[D_MODEL];                               // SCALE*b_up
    __shared__ float s_G [BN];
    __shared__ float s_DB[BN];
    __shared__ float s_red[WAVES][32];

    const int t    = threadIdx.x;
    const int w    = t >> 6;
    const int lane = t & 63;
    const int kcol = lane & 15;
    const int q    = lane >> 4;

    // ---------------- staging (once per block) ----------------
    float Gp[BN], Dp[BN];
    #pragma unroll
    for (int k = 0; k < BN; ++k) { Gp[k] = 0.f; Dp[k] = 0.f; }

    #pragma unroll
    for (int i = 0; i < 3; ++i) {
        const int d = t + 256 * i;
        float wv[16];
        ld4(w_down + (size_t)d * BN + 0,  wv + 0);
        ld4(w_down + (size_t)d * BN + 4,  wv + 4);
        ld4(w_down + (size_t)d * BN + 8,  wv + 8);
        ld4(w_down + (size_t)d * BN + 12, wv + 12);
        const float gd = gamma[d];
        const float bd = beta[d];
        #pragma unroll
        for (int k = 0; k < BN; ++k) {
            const float gw = gd * wv[k];
            Gp[k] = fmaf(gd, wv[k], Gp[k]);
            Dp[k] = fmaf(bd, wv[k], Dp[k]);
            s_wdb[k][d] = f2bf(gw);
        }
        #pragma unroll
        for (int k = 0; k < BN; ++k)
            s_wub[d][k] = f2bf(SCALE * w_up[(size_t)k * D_MODEL + d]);
        // zero this row's pad shorts 16..23 (read by q==2 lanes)
        *(uint4*)&s_wub[d][16] = make_uint4(0u, 0u, 0u, 0u);
        s_sbu[d] = SCALE * b_up[d];
    }
    if (t < 2) {   // guard rows for q==3 read at d=767
        *(uint4*)&s_wub[768 + t][0]  = make_uint4(0u, 0u, 0u, 0u);
        *(uint4*)&s_wub[768 + t][8]  = make_uint4(0u, 0u, 0u, 0u);
        *(uint4*)&s_wub[768 + t][16] = make_uint4(0u, 0u, 0u, 0u);
    }
    if (t < WAVES * 17) {   // zero dn pads (q>=2 reads)
        const int wv2 = t / 17, r = t % 17;
        *(uint4*)&s_dn2[wv2][r][16] = make_uint4(0u, 0u, 0u, 0u);
        if (r == 16) {
            *(uint4*)&s_dn2[wv2][16][0] = make_uint4(0u, 0u, 0u, 0u);
            *(uint4*)&s_dn2[wv2][16][8] = make_uint4(0u, 0u, 0u, 0u);
        }
    }

    // wave-reduce G/D partials (register shfl, no LDS pressure)
    #pragma unroll
    for (int m = 32; m >= 1; m >>= 1) {
        #pragma unroll
        for (int k = 0; k < BN; ++k) {
            Gp[k] += __shfl_xor(Gp[k], m, 64);
            Dp[k] += __shfl_xor(Dp[k], m, 64);
        }
    }
    if (lane == 0) {
        #pragma unroll
        for (int k = 0; k < BN; ++k) {
            s_red[w][k]      = Gp[k];
            s_red[w][16 + k] = Dp[k];
        }
    }
    __syncthreads();
    if (t < BN) {
        s_G[t]  = s_red[0][t] + s_red[1][t] + s_red[2][t] + s_red[3][t];
        s_DB[t] = s_red[0][16 + t] + s_red[1][16 + t] + s_red[2][16 + t]
                + s_red[3][16 + t] + b_down[t];
    }
    __syncthreads();

    // ---------------- main: one wave = 16 rows ----------------
    const int   r0    = blockIdx.x * ROWS_PER_BLOCK + w * 16;
    const float kG    = s_G[kcol];
    const float kDB   = s_DB[kcol];
    const float inv_d = 1.0f / (float)D_MODEL;

    // ---- DOWN: P[16x16] = bf16(x) @ bf16(g*wd), fp32 acc; stats alongside.
    // A-frag: lane row = kcol, k = q*8+j (x row-major -> 2 float4 per chunk).
    f32x4 P = {0.f, 0.f, 0.f, 0.f};
    float s1 = 0.f, s2 = 0.f;
    const float* xrow = x + (size_t)(r0 + kcol) * D_MODEL + q * 8;
    const unsigned short* wdl = &s_wdb[kcol][q * 8];
    #pragma unroll
    for (int tt = 0; tt < KCH; ++tt) {
        float xf[8];
        ld4(xrow + tt * 32,     xf);
        ld4(xrow + tt * 32 + 4, xf + 4);
        bf16x8 a;
        #pragma unroll
        for (int j = 0; j < 8; ++j) {
            s1 += xf[j];
            s2  = fmaf(xf[j], xf[j], s2);
            a[j] = (short)f2bf(xf[j]);
        }
        bf16x8 b = *(const bf16x8*)(wdl + tt * 32);   // 64B chunk stride
        P = __builtin_amdgcn_mfma_f32_16x16x32_bf16(a, b, P, 0, 0, 0);
    }

    // row stats: partials live in lanes {r, r+16, r+32, r+48} -> 2 shfls
    s1 += __shfl_xor(s1, 16, 64); s1 += __shfl_xor(s1, 32, 64);
    s2 += __shfl_xor(s2, 16, 64); s2 += __shfl_xor(s2, 32, 64);
    const float mean = s1 * inv_d;
    const float rs   = rsqrtf(fmaf(s2, inv_d, -(mean * mean)) + LN_EPS);

    // C-layout: lane holds rows q*4+reg, col kcol -> fetch those rows' stats
    float mj[4], rj[4];
    #pragma unroll
    for (int i = 0; i < 4; ++i) {
        mj[i] = __shfl(mean, q * 4 + i, 64);
        rj[i] = __shfl(rs,   q * 4 + i, 64);
    }
    #pragma unroll
    for (int reg = 0; reg < 4; ++reg) {
        const float dv = fmaxf(fmaf(rj[reg], fmaf(-mj[reg], kG, P[reg]), kDB), 0.f);
        s_dn2[w][q * 4 + reg][kcol] = f2bf(dv);   // transpose via wave-local LDS
    }

    // A-frag for UP: lane row = kcol, k = q*8+j (q>=2 -> zero, K padded to 32)
    bf16x8 a2 = *(const bf16x8*)&s_dn2[w][kcol][q * 8];
    if (lane >= 32) {
        #pragma unroll
        for (int j = 0; j < 8; ++j) a2[j] = 0;
    }

    // ---- UP: out[16 x 768] = dn @ (SCALE*wu) + (x + SCALE*b_up) ----
    const float* xres = x   + (size_t)(r0 + q * 4) * D_MODEL + kcol;
    float*       ores = out + (size_t)(r0 + q * 4) * D_MODEL + kcol;
    #pragma unroll 6
    for (int c = 0; c < 48; ++c) {
        const int dcol = c * 16 + kcol;
        const float sb = s_sbu[dcol];
        f32x4 cin;
        #pragma unroll
        for (int reg = 0; reg < 4; ++reg)
            cin[reg] = xres[(size_t)reg * D_MODEL + c * 16] + sb;
        bf16x8 b2 = *(const bf16x8*)&s_wub[dcol][q * 8];
        f32x4 o = __builtin_amdgcn_mfma_f32_16x16x32_bf16(a2, b2, cin, 0, 0, 0);
        #pragma unroll
        for (int reg = 0; reg < 4; ++reg)
            ores[(size_t)reg * D_MODEL + c * 16] = o[reg];
    }
}

extern "C" void kernel_launch(void* const* d_in, const int* in_sizes, int n_in,
                              void* d_out, int out_size, void* d_ws, size_t ws_size,
                              hipStream_t stream) {
    const float* x       = (const float*)d_in[0];
    const float* gamma   = (const float*)d_in[1];
    const float* beta    = (const float*)d_in[2];
    const float* w_down  = (const float*)d_in[3];
    const float* b_down  = (const float*)d_in[4];
    const float* w_up    = (const float*)d_in[5];
    const float* b_up    = (const float*)d_in[6];
    float* out = (float*)d_out;

    adapter_fused<<<NBLOCKS, TPB, 0, stream>>>(x, gamma, beta, w_down, b_down,
                                               w_up, b_up, out);
}